// Round 16
// baseline (161.384 us; speedup 1.0000x reference)
//
#include <hip/hip_runtime.h>
#include <cstdint>
#include <cstddef>

#define NC 64
#define LN2 0.6931471805599453f

typedef _Float16 half2_t __attribute__((ext_vector_type(2)));
typedef unsigned int uint32x4 __attribute__((ext_vector_type(4)));

static __device__ __forceinline__ float dot2acc(uint32_t a, uint32_t b, float c) {
#if __has_builtin(__builtin_amdgcn_fdot2)
    return __builtin_amdgcn_fdot2(__builtin_bit_cast(half2_t, a),
                                  __builtin_bit_cast(half2_t, b), c, false);
#else
    half2_t ha = __builtin_bit_cast(half2_t, a), hb = __builtin_bit_cast(half2_t, b);
    return c + (float)ha[0] * (float)hb[0] + (float)ha[1] * (float)hb[1];
#endif
}

template <int CTRL>
static __device__ __forceinline__ float dppf(float x) {
    return __int_as_float(__builtin_amdgcn_update_dpp(
        0, __float_as_int(x), CTRL, 0xf, 0xf, true));
}
static __device__ __forceinline__ float wave_sum_bcast(float x) {
    x = x + dppf<0x111>(x);
    x = x + dppf<0x112>(x);
    x = x + dppf<0x114>(x);
    x = x + dppf<0x118>(x);
    x = x + dppf<0x142>(x);   // row_bcast15
    x = x + dppf<0x143>(x);   // row_bcast31
    return __int_as_float(__builtin_amdgcn_readlane(__float_as_int(x), 63));
}

// DPP ctrls: 0xB1 ^1 (quad), 0x4E ^2 (quad), 0x141 ^7 (half_mirror), 0x140 ^15 (mirror)

__global__ __launch_bounds__(64, 1)
void crf_nll_kernel(const float* __restrict__ logits,
                    const float* __restrict__ trans,
                    const float* __restrict__ init_alphas,
                    const int*  __restrict__ lengths,
                    const int*  __restrict__ tags,
                    float* __restrict__ out,
                    int N, int T)
{
    const int n = blockIdx.x;
    const int lane = threadIdx.x;      // 0..63; ONE wave runs BOTH chains
    const float* lg = logits + (size_t)n * T * NC;
    const int len = lengths[n];        // in [2, T]
    const int Tm1 = T - 1;

    __shared__ __align__(16) uint32_t Etab[2][64 * 32]; // [0]=E rows, [1]=E^T rows (split-dot layout)
    __shared__ __align__(16) uint16_t st_pk[2][NC + 8]; // [0]=fwd state, [1]=bwd state (f16)

    // ---- fill both tables (round-12 layout, verified):
    // lane i, word (j,k): E-row (i^D(j)), classes (8s+2k, 8s+2k+1);
    // D(j) = (j&3)|((j&4)<<1); s(i) = (i&3)|((i>>1)&4)
    #pragma unroll
    for (int idx = lane; idx < 2 * 64 * 32; idx += 64) {
        int tab = idx >> 11, rem = idx & 2047;
        int i = rem >> 5, wrd = rem & 31;
        int j = wrd >> 2, k = wrd & 3;
        int D = (j & 3) | ((j & 4) << 1);
        int row = i ^ D;
        int s = (i & 3) | ((i >> 1) & 4);
        int c0 = 8 * s + 2 * k, c1 = c0 + 1;
        float x0 = tab == 0 ? trans[row * NC + c0] : trans[c0 * NC + row];
        float x1 = tab == 0 ? trans[row * NC + c1] : trans[c1 * NC + row];
        uint32_t lo = (uint32_t)__builtin_bit_cast(uint16_t, (_Float16)__expf(x0));
        uint32_t hi = (uint32_t)__builtin_bit_cast(uint16_t, (_Float16)__expf(x1));
        Etab[tab][i * 32 + wrd] = lo | (hi << 16);
    }
    // single wave: DS pipe in-order -> no barrier needed

    // ---- hoist BOTH 128B E blocks into 16 vec4 regs via inline asm (round-8 mechanism)
    uint32x4 f0, f1, f2, f3, f4, f5, f6, f7;    // forward E
    uint32x4 b0, b1, b2, b3, b4, b5, b6, b7;    // backward E^T
    {
        uint32_t ea = (uint32_t)(uintptr_t)&Etab[0][0] + (uint32_t)(lane * 128);
        asm volatile(
            "ds_read_b128 %0, %8 offset:0\n\t"
            "ds_read_b128 %1, %8 offset:16\n\t"
            "ds_read_b128 %2, %8 offset:32\n\t"
            "ds_read_b128 %3, %8 offset:48\n\t"
            "ds_read_b128 %4, %8 offset:64\n\t"
            "ds_read_b128 %5, %8 offset:80\n\t"
            "ds_read_b128 %6, %8 offset:96\n\t"
            "ds_read_b128 %7, %8 offset:112\n\t"
            "s_waitcnt lgkmcnt(0)"
            : "=&v"(f0), "=&v"(f1), "=&v"(f2), "=&v"(f3),
              "=&v"(f4), "=&v"(f5), "=&v"(f6), "=&v"(f7)
            : "v"(ea) : "memory");
        uint32_t eb = (uint32_t)(uintptr_t)&Etab[1][0] + (uint32_t)(lane * 128);
        asm volatile(
            "ds_read_b128 %0, %8 offset:0\n\t"
            "ds_read_b128 %1, %8 offset:16\n\t"
            "ds_read_b128 %2, %8 offset:32\n\t"
            "ds_read_b128 %3, %8 offset:48\n\t"
            "ds_read_b128 %4, %8 offset:64\n\t"
            "ds_read_b128 %5, %8 offset:80\n\t"
            "ds_read_b128 %6, %8 offset:96\n\t"
            "ds_read_b128 %7, %8 offset:112\n\t"
            "s_waitcnt lgkmcnt(0)"
            : "=&v"(b0), "=&v"(b1), "=&v"(b2), "=&v"(b3),
              "=&v"(b4), "=&v"(b5), "=&v"(b6), "=&v"(b7)
            : "v"(eb) : "memory");
        __builtin_amdgcn_sched_barrier(0);
    }

    const int m  = (len - 1) >> 1;     // forward steps; backward nb = m or m+1
    const int nb = len - 1 - m;

    const int s_lane = (lane & 3) | ((lane >> 1) & 4);
    const uint32x4* wch_f = reinterpret_cast<const uint32x4*>(st_pk[0] + 8 * s_lane);
    const uint32x4* wch_b = reinterpret_cast<const uint32x4*>(st_pk[1] + 8 * s_lane);

    // split-dot + verified DPP tree (round 12 verbatim), per-table
#define DOTE(WCH, E0, E1, E2, E3, E4, E5, E6, E7, OUT)                                           \
    {                                                                                            \
        const uint32x4 w = (WCH)[0];                                                             \
        float p0, p1, p2, p3, p4, p5, p6, p7;                                                    \
        p0 = dot2acc(E0.x, w.x, dot2acc(E0.y, w.y, dot2acc(E0.z, w.z, dot2acc(E0.w, w.w, 0.f)))); \
        p1 = dot2acc(E1.x, w.x, dot2acc(E1.y, w.y, dot2acc(E1.z, w.z, dot2acc(E1.w, w.w, 0.f)))); \
        p2 = dot2acc(E2.x, w.x, dot2acc(E2.y, w.y, dot2acc(E2.z, w.z, dot2acc(E2.w, w.w, 0.f)))); \
        p3 = dot2acc(E3.x, w.x, dot2acc(E3.y, w.y, dot2acc(E3.z, w.z, dot2acc(E3.w, w.w, 0.f)))); \
        p4 = dot2acc(E4.x, w.x, dot2acc(E4.y, w.y, dot2acc(E4.z, w.z, dot2acc(E4.w, w.w, 0.f)))); \
        p5 = dot2acc(E5.x, w.x, dot2acc(E5.y, w.y, dot2acc(E5.z, w.z, dot2acc(E5.w, w.w, 0.f)))); \
        p6 = dot2acc(E6.x, w.x, dot2acc(E6.y, w.y, dot2acc(E6.z, w.z, dot2acc(E6.w, w.w, 0.f)))); \
        p7 = dot2acc(E7.x, w.x, dot2acc(E7.y, w.y, dot2acc(E7.z, w.z, dot2acc(E7.w, w.w, 0.f)))); \
        float q0  = p0 + dppf<0xB1>(p1);                                                         \
        float q2  = p2 + dppf<0xB1>(p3);                                                         \
        float q8  = p4 + dppf<0xB1>(p5);                                                         \
        float q10 = p6 + dppf<0xB1>(p7);                                                         \
        float r0 = q0 + dppf<0x4E>(q2);                                                          \
        float r8 = q8 + dppf<0x4E>(q10);                                                         \
        float t8 = dppf<0x141>(r8);                                                              \
        OUT = r0 + dppf<0x140>(t8);                                                              \
    }

    // ---- init both chains
    float a0 = init_alphas[lane] + lg[lane];
    float L_f = __int_as_float(__builtin_amdgcn_readfirstlane(__float_as_int(a0))) + 8.f * LN2;
    float v_f = __expf(a0 - L_f);
    st_pk[0][lane] = __builtin_bit_cast(uint16_t, (_Float16)v_f);
    float s_f = 1.0f, dL_f = 0.0f;

    float L_b = 0.f, v_b = 1.0f, s_b = 1.0f, dL_b = 0.0f;

    auto fstep = [&](float raw) {
        float fs = __expf(raw) * s_f;
        L_f += dL_f;
        float dt; DOTE(wch_f, f0, f1, f2, f3, f4, f5, f6, f7, dt)
        float v = fs * dt;
        v_f = v;
        st_pk[0][lane] = __builtin_bit_cast(uint16_t, (_Float16)v);
        unsigned bits = (unsigned)__builtin_amdgcn_readfirstlane((int)__float_as_uint(v));
        int e = (int)((bits >> 23) & 0xFF);
        s_f  = __uint_as_float((unsigned)(246 - e) << 23);    // 2^(119-e)
        dL_f = (float)(e - 119) * LN2;
    };
    auto bstep = [&](float raw) {
        float p = __expf(raw) * s_b * v_b;
        L_b += dL_b;
        st_pk[1][lane] = __builtin_bit_cast(uint16_t, (_Float16)p);
        float u; DOTE(wch_b, b0, b1, b2, b3, b4, b5, b6, b7, u)
        v_b = u;
        unsigned bits = (unsigned)__builtin_amdgcn_readfirstlane((int)__float_as_uint(u));
        int e = (int)((bits >> 23) & 0xFF);
        s_b  = __uint_as_float((unsigned)(246 - e) << 23);    // 2^(119-e)
        dL_b = (float)(e - 119) * LN2;
    };

    // ---- depth-8 prefetch for BOTH chains in named registers
    float rf0 = lg[NC * (1 < Tm1 ? 1 : Tm1) + lane];
    float rf1 = lg[NC * (2 < Tm1 ? 2 : Tm1) + lane];
    float rf2 = lg[NC * (3 < Tm1 ? 3 : Tm1) + lane];
    float rf3 = lg[NC * (4 < Tm1 ? 4 : Tm1) + lane];
    float rf4 = lg[NC * (5 < Tm1 ? 5 : Tm1) + lane];
    float rf5 = lg[NC * (6 < Tm1 ? 6 : Tm1) + lane];
    float rf6 = lg[NC * (7 < Tm1 ? 7 : Tm1) + lane];
    float rf7 = lg[NC * (8 < Tm1 ? 8 : Tm1) + lane];
    int pi;
    pi = len - 1; pi = pi > 1 ? pi : 1; float rb0 = lg[NC * pi + lane];
    pi = len - 2; pi = pi > 1 ? pi : 1; float rb1 = lg[NC * pi + lane];
    pi = len - 3; pi = pi > 1 ? pi : 1; float rb2 = lg[NC * pi + lane];
    pi = len - 4; pi = pi > 1 ? pi : 1; float rb3 = lg[NC * pi + lane];
    pi = len - 5; pi = pi > 1 ? pi : 1; float rb4 = lg[NC * pi + lane];
    pi = len - 6; pi = pi > 1 ? pi : 1; float rb5 = lg[NC * pi + lane];
    pi = len - 7; pi = pi > 1 ? pi : 1; float rb6 = lg[NC * pi + lane];
    pi = len - 8; pi = pi > 1 ? pi : 1; float rb7 = lg[NC * pi + lane];

    // joint loop: iteration t does fwd step t (t<=m) and bwd step k=t-1 (t<=nb); nb>=m
    int t = 1;
#define SLOT(i, RF, RB)                                                            \
    fstep(RF); bstep(RB);                                                          \
    pi = t + (i) + 8; pi = pi < Tm1 ? pi : Tm1; RF = lg[NC * pi + lane];           \
    pi = len - 8 - t - (i); pi = pi > 1 ? pi : 1; RB = lg[NC * pi + lane];
    for (; t + 8 <= m + 1; t += 8) {
        SLOT(0, rf0, rb0)
        SLOT(1, rf1, rb1)
        SLOT(2, rf2, rb2)
        SLOT(3, rf3, rb3)
        SLOT(4, rf4, rb4)
        SLOT(5, rf5, rb5)
        SLOT(6, rf6, rb6)
        SLOT(7, rf7, rb7)
    }
#undef SLOT
    // tail: fwd slots 0..6 (t+i<=m), bwd slots 0..7 (t+i<=nb, nb<=m+1)
    if (t + 0 <= m) fstep(rf0);
    if (t + 0 <= nb) bstep(rb0);
    if (t + 1 <= m) fstep(rf1);
    if (t + 1 <= nb) bstep(rb1);
    if (t + 2 <= m) fstep(rf2);
    if (t + 2 <= nb) bstep(rb2);
    if (t + 3 <= m) fstep(rf3);
    if (t + 3 <= nb) bstep(rb3);
    if (t + 4 <= m) fstep(rf4);
    if (t + 4 <= nb) bstep(rb4);
    if (t + 5 <= m) fstep(rf5);
    if (t + 5 <= nb) bstep(rb5);
    if (t + 6 <= m) fstep(rf6);
    if (t + 6 <= nb) bstep(rb6);
    if (t + 7 <= nb) bstep(rb7);

    // ---- combine: logZ = L_f + L_b + log(sum_j vf[j] * vb[j])  (all wave-local!)
    float prod = v_f * v_b;
    float ssum = wave_sum_bcast(prod);
    const float logZ = L_f + L_b + __logf(ssum);

    // ---- gold score (lane-strided, off critical path)
    const int* tg = tags + (size_t)n * T;
    float g = 0.f;
    for (int tt = 1 + lane; tt < len; tt += 64) {
        const int cur = tg[tt];
        const int prv = tg[tt - 1];
        g += trans[cur * NC + prv] + lg[tt * NC + cur];
    }
    g = wave_sum_bcast(g);

    if (lane == 0) {
        const int t0 = tg[0];
        const float gold = init_alphas[t0] + lg[t0] + g;
        out[n] = logZ - gold;
    }
}

extern "C" void kernel_launch(void* const* d_in, const int* in_sizes, int n_in,
                              void* d_out, int out_size, void* d_ws, size_t ws_size,
                              hipStream_t stream)
{
    const float* logits = (const float*)d_in[0];   // [N][T][C] f32
    const float* trans  = (const float*)d_in[1];   // [C][C]    f32
    const float* inita  = (const float*)d_in[2];   // [C]       f32
    const int*   lens   = (const int*)d_in[3];     // [N]       i32
    const int*   tags   = (const int*)d_in[4];     // [N][T]    i32
    float*       out    = (float*)d_out;           // [N]       f32

    const int N = 512, T = 1024;
    crf_nll_kernel<<<N, 64, 0, stream>>>(logits, trans, inita, lens, tags, out, N, T);
}